// Round 6
// baseline (42.765 us; speedup 1.0000x reference)
//
#include <hip/hip_runtime.h>
#include <cmath>

// LatencyEncoder: out[b, t, n] = (t == floor(clip(-TAU*log(sigmoid(x[b,n])+EPS), 0, T-1))) ? 1 : 0
// B=256, N=4096, T=64. Output 256 MiB fp32 -> write-BW bound.
// R5: occupancy 16 -> 32 waves/CU (512-thread blocks, 2 n/thread, float2 stores) to hide
//     the x-load latency ramp at dispatch start. No change in HBM traffic.
// History: R0 41.67us baseline; R2 nt stores -24% (keep L2 in write path);
//          R3 contiguous 256KB blocks -8%; R4 host threshold table (exact f32 compare) 40.94us.

#define B_DIM 256
#define N_DIM 4096
#define T_DIM 64

typedef float f32x2 __attribute__((ext_vector_type(2)));

struct ThreshTab { float c[65]; };  // c[0]=+INF, c[k] k=1..63 decreasing, c[64]=-INF

__global__ __launch_bounds__(512) void latency_encoder_kernel(
    const float* __restrict__ x, float* __restrict__ out, ThreshTab tab)
{
    __shared__ float C[65];
    const int tid = threadIdx.x;
    if (tid < 65) C[tid] = tab.c[tid];
    __syncthreads();

    const int b  = blockIdx.y;
    const int n0 = (blockIdx.x * 512 + tid) * 2;  // 2 consecutive n per thread

    const f32x2 xv = *reinterpret_cast<const f32x2*>(x + (size_t)b * N_DIM + n0);

    int t[2];
#pragma unroll
    for (int i = 0; i < 2; ++i) {
        const float xf = xv[i];
        // Fast f32 estimate (hw exp/log). Worst-case lat error ~3e-5 << 1 -> t off by <=1.
        const float e  = __expf(-xf);             // overflow to +inf ok: s->0, lat huge->clamp
        const float s  = 1.0f / (1.0f + e);
        const float lat = -10.0f * __logf(s + 1e-7f);
        int th = (int)lat;
        th = th < 0 ? 0 : (th > 63 ? 63 : th);
        // Exact fixup vs host-f64 thresholds: correct t satisfies x <= C[t] and x > C[t+1].
        const float chi = C[th];
        const float clo = C[th + 1];
        th += (xf <= clo) ? 1 : ((xf > chi) ? -1 : 0);
        t[i] = th;
    }

    // 64 coalesced float2 stores (512B per wave-store; issue rate has ~10x headroom).
    f32x2* outp = reinterpret_cast<f32x2*>(out + (size_t)b * (T_DIM * N_DIM) + n0);
#pragma unroll
    for (int tt = 0; tt < T_DIM; ++tt) {
        f32x2 v;
        v.x = (tt == t[0]) ? 1.0f : 0.0f;
        v.y = (tt == t[1]) ? 1.0f : 0.0f;
        outp[(size_t)tt * (N_DIM / 2)] = v;
    }
}

extern "C" void kernel_launch(void* const* d_in, const int* in_sizes, int n_in,
                              void* d_out, int out_size, void* d_ws, size_t ws_size,
                              hipStream_t stream)
{
    const float* x = (const float*)d_in[0];
    float* out = (float*)d_out;

    // Host-side exact threshold table (deterministic, pure CPU math — graph-capture safe).
    ThreshTab tab;
    tab.c[0]  =  INFINITY;
    tab.c[64] = -INFINITY;
    for (int k = 1; k <= 63; ++k) {
        const double Sk = exp(-(double)k / 10.0) - 1e-7;   // sigmoid threshold, in (0,1)
        const double Ek = log(Sk / (1.0 - Sk));            // x threshold (logit), f64
        float c = (float)Ek;
        if ((double)c > Ek) c = nextafterf(c, -INFINITY);  // largest f32 <= Ek
        tab.c[k] = c;
    }

    // 4096 n / (512 threads * 2 per thread) = 4 blocks per row, 256 rows.
    // 1024 blocks x 8 waves = 4 blocks/CU -> 32 waves/CU (was 16).
    dim3 grid(N_DIM / (512 * 2), B_DIM);
    latency_encoder_kernel<<<grid, 512, 0, stream>>>(x, out, tab);
}

// Round 7
// 40.665 us; speedup vs baseline: 1.0516x; 1.0516x over previous
//
#include <hip/hip_runtime.h>
#include <cmath>

// LatencyEncoder: out[b, t, n] = (t == floor(clip(-TAU*log(sigmoid(x[b,n])+EPS), 0, T-1))) ? 1 : 0
// B=256, N=4096, T=64. Output 256 MiB fp32 -> write-BW bound.
// R6: occupancy 16 -> 32 waves/CU WITHOUT narrowing stores: split T into 2 halves,
//     2048 blocks x 256 thr, 4 n/thread, 32 float4 stores each. x read twice (negligible).
// History: R0 41.67; R2 nt stores -24%; R3 contiguous blocks -8%;
//          R4 host threshold table 40.94 (best); R5 float2/512thr 42.76 (narrow stores hurt).

#define B_DIM 256
#define N_DIM 4096
#define T_DIM 64
#define T_SPLIT 2
#define T_CHUNK (T_DIM / T_SPLIT)   // 32 t-steps per block

typedef float f32x4 __attribute__((ext_vector_type(4)));

struct ThreshTab { float c[65]; };  // c[0]=+INF, c[k] k=1..63 decreasing, c[64]=-INF

__global__ __launch_bounds__(256) void latency_encoder_kernel(
    const float* __restrict__ x, float* __restrict__ out, ThreshTab tab)
{
    __shared__ float C[65];
    const int tid = threadIdx.x;
    if (tid < 65) C[tid] = tab.c[tid];
    __syncthreads();

    const int b      = blockIdx.y;
    const int nchunk = blockIdx.x >> 1;          // 0..3
    const int tstart = (blockIdx.x & 1) * T_CHUNK; // 0 or 32
    const int n0     = (nchunk * 256 + tid) * 4; // 4 consecutive n per thread

    const f32x4 xv = *reinterpret_cast<const f32x4*>(x + (size_t)b * N_DIM + n0);

    int t[4];
#pragma unroll
    for (int i = 0; i < 4; ++i) {
        const float xf = xv[i];
        // Fast f32 estimate (hw exp/log); worst-case lat error ~3e-5 << 1 -> t off by <=1.
        const float e  = __expf(-xf);
        const float s  = 1.0f / (1.0f + e);
        const float lat = -10.0f * __logf(s + 1e-7f);
        int th = (int)lat;
        th = th < 0 ? 0 : (th > 63 ? 63 : th);
        // Exact fixup vs host-f64 thresholds: correct t satisfies x <= C[t] and x > C[t+1].
        const float chi = C[th];
        const float clo = C[th + 1];
        th += (xf <= clo) ? 1 : ((xf > chi) ? -1 : 0);
        t[i] = th;
    }

    // 32 coalesced float4 stores for this block's half of the time axis.
    f32x4* outp = reinterpret_cast<f32x4*>(out + (size_t)b * (T_DIM * N_DIM) + n0);
#pragma unroll
    for (int k = 0; k < T_CHUNK; ++k) {
        const int tt = tstart + k;
        f32x4 v;
        v.x = (tt == t[0]) ? 1.0f : 0.0f;
        v.y = (tt == t[1]) ? 1.0f : 0.0f;
        v.z = (tt == t[2]) ? 1.0f : 0.0f;
        v.w = (tt == t[3]) ? 1.0f : 0.0f;
        outp[(size_t)tt * (N_DIM / 4)] = v;
    }
}

extern "C" void kernel_launch(void* const* d_in, const int* in_sizes, int n_in,
                              void* d_out, int out_size, void* d_ws, size_t ws_size,
                              hipStream_t stream)
{
    const float* x = (const float*)d_in[0];
    float* out = (float*)d_out;

    // Host-side exact threshold table (deterministic, pure CPU math — graph-capture safe).
    ThreshTab tab;
    tab.c[0]  =  INFINITY;
    tab.c[64] = -INFINITY;
    for (int k = 1; k <= 63; ++k) {
        const double Sk = exp(-(double)k / 10.0) - 1e-7;   // sigmoid threshold, in (0,1)
        const double Ek = log(Sk / (1.0 - Sk));            // x threshold (logit), f64
        float c = (float)Ek;
        if ((double)c > Ek) c = nextafterf(c, -INFINITY);  // largest f32 <= Ek
        tab.c[k] = c;
    }

    // grid.x = 4 n-chunks x 2 t-halves = 8; 2048 blocks total -> 8 blocks/CU = 32 waves/CU.
    dim3 grid(8, B_DIM);
    latency_encoder_kernel<<<grid, 256, 0, stream>>>(x, out, tab);
}